// Round 4
// baseline (52.944 us; speedup 1.0000x reference)
//
#include <hip/hip_runtime.h>

#define WINDOW 20
#define EPS 1e-8f

constexpr int B = 16;
constexpr int F = 257;
constexpr int T = 8000;
constexpr int TQ = T / 4;                          // 2000 quads per row
constexpr int CHUNK_Q = 32;                        // 128 columns per block
constexpr int NTILES = (TQ + CHUNK_Q - 1) / CHUNK_Q;  // 63

// Fused single-read: each block owns (b, 128 columns).
// 1024 threads = 32 row-groups x 32 quads; each thread holds 8 rows in regs.
__global__ void __launch_bounds__(1024) fused_kernel(
    const float* __restrict__ mag, const float* __restrict__ bias,
    float* __restrict__ out_norm, float* __restrict__ out_mean) {

  const int b    = blockIdx.y;
  const int q0   = blockIdx.x * CHUNK_Q;
  const int tid  = threadIdx.x;
  const int q    = tid & (CHUNK_Q - 1);   // quad within chunk 0..31
  const int rg   = tid >> 5;              // row group 0..31
  const int wave = tid >> 6;              // 0..15
  const int lane = tid & 63;

  const float4* magq = (const float4*)(mag + (size_t)b * F * T);
  float4* outq = (float4*)(out_norm + (size_t)b * F * T);
  const float bs = bias[0];

  __shared__ float4 red[32][CHUNK_Q];      // 16 KB: [rg][q] partial col sums
  __shared__ float  cs[20 + CHUNK_Q * 4];  // [0..19] halo, [20..147] chunk
  __shared__ float4 inv4[CHUNK_Q];

  // ---- left-halo column sums: waves 0..4 each handle one halo quad ----
  if (wave < 5) {
    int qh = q0 - 5 + wave;
    float4 hs = make_float4(0.f, 0.f, 0.f, 0.f);
    if (qh >= 0) {
      #pragma unroll
      for (int r = 0; r < 4; ++r) {
        float4 tv = magq[(size_t)(lane + (r << 6)) * TQ + qh];
        hs.x += tv.x; hs.y += tv.y; hs.z += tv.z; hs.w += tv.w;
      }
      if (lane == 0) {
        float4 tv = magq[(size_t)256 * TQ + qh];
        hs.x += tv.x; hs.y += tv.y; hs.z += tv.z; hs.w += tv.w;
      }
    }
    #pragma unroll
    for (int off = 32; off > 0; off >>= 1) {
      hs.x += __shfl_down(hs.x, off);
      hs.y += __shfl_down(hs.y, off);
      hs.z += __shfl_down(hs.z, off);
      hs.w += __shfl_down(hs.w, off);
    }
    if (lane == 0) {
      cs[4 * wave + 0] = hs.x;
      cs[4 * wave + 1] = hs.y;
      cs[4 * wave + 2] = hs.z;
      cs[4 * wave + 3] = hs.w;
    }
  }
  // fenced by sync A before cs halo is read

  const int qc  = min(CHUNK_Q, TQ - q0);
  const bool act = (q < qc);

  // ---- load chunk into registers + per-thread column partials ----
  float4 v[8];
  float4 v16 = make_float4(0.f, 0.f, 0.f, 0.f);
  float4 acc = make_float4(0.f, 0.f, 0.f, 0.f);
  if (act) {
    const float4* p = magq + q0 + q;
    #pragma unroll
    for (int it = 0; it < 8; ++it) {
      float4 tv = p[(size_t)(rg + (it << 5)) * TQ];
      v[it] = tv;
      acc.x += tv.x; acc.y += tv.y; acc.z += tv.z; acc.w += tv.w;
    }
    if (rg == 0) {                         // fold row f=256
      v16 = p[(size_t)256 * TQ];
      acc.x += v16.x; acc.y += v16.y; acc.z += v16.z; acc.w += v16.w;
    }
  }
  red[rg][q] = acc;
  __syncthreads();                         // A

  // ---- finalize column sums (32 threads) ----
  if (tid < CHUNK_Q) {
    float4 s = make_float4(0.f, 0.f, 0.f, 0.f);
    #pragma unroll
    for (int r = 0; r < 32; ++r) {
      float4 a = red[r][tid];
      s.x += a.x; s.y += a.y; s.z += a.z; s.w += a.w;
    }
    cs[20 + 4 * tid + 0] = s.x;
    cs[20 + 4 * tid + 1] = s.y;
    cs[20 + 4 * tid + 2] = s.z;
    cs[20 + 4 * tid + 3] = s.w;
  }
  __syncthreads();                         // B

  // ---- window means + inverse ----
  const int ncols = qc * 4;
  if (tid < ncols) {
    int t = q0 * 4 + tid;
    float ws = 0.f;
    #pragma unroll
    for (int k = 0; k < WINDOW; ++k) ws += cs[20 + tid - k];
    int nwin = (t < WINDOW - 1) ? (t + 1) : WINDOW;
    float mean = ws / (float)(nwin * F) + bs;
    out_mean[b * T + t] = mean;
    ((float*)inv4)[tid] = 1.0f / (mean + EPS);
  }
  __syncthreads();                         // C

  // ---- normalize from registers + store ----
  if (act) {
    float4 w = inv4[q];
    float4* o = outq + q0 + q;
    #pragma unroll
    for (int it = 0; it < 8; ++it) {
      float4 tv = v[it];
      tv.x *= w.x; tv.y *= w.y; tv.z *= w.z; tv.w *= w.w;
      o[(size_t)(rg + (it << 5)) * TQ] = tv;
    }
    if (rg == 0) {
      float4 tv = v16;
      tv.x *= w.x; tv.y *= w.y; tv.z *= w.z; tv.w *= w.w;
      o[(size_t)256 * TQ] = tv;
    }
  }
}

extern "C" void kernel_launch(void* const* d_in, const int* in_sizes, int n_in,
                              void* d_out, int out_size, void* d_ws, size_t ws_size,
                              hipStream_t stream) {
  const float* mag  = (const float*)d_in[0];
  const float* bias = (const float*)d_in[1];
  float* out_norm = (float*)d_out;                      // B*F*T floats
  float* out_mean = (float*)d_out + (size_t)B * F * T;  // B*T floats

  dim3 grid(NTILES, B);
  fused_kernel<<<grid, 1024, 0, stream>>>(mag, bias, out_norm, out_mean);
}